// Round 10
// baseline (213.195 us; speedup 1.0000x reference)
//
#include <hip/hip_runtime.h>

// NormEMAVectorQuantizer on MI355X (gfx950)
// N=8192 tokens, C=32, K=8192 codes, B=32, H*W=256.
// R10: k_max (bf16-MFMA sweep) -> pmax[chunk][tok]. k_pick2: HALF-WAVE per
// token (1024 blocks, no LDS, no barriers): 32 lanes load the token's 32
// chunk maxima, shuffle-reduce gmax, ballot qualifying chunks
// (pmax >= gmax-eps, ~1.05/token); each lane rescores 8 consecutive codes
// of each qualifying chunk with exact fp32 dots; 5-level u64 (score,code)
// shuffle reduce; lane 0 stores ids/pos (8K scattered atomicAdd on bins).
// Certificate: bf16 dot err <= 2*2^-9 = 0.0078 < eps=0.01 for unit rows, so
// the chunk of the fp32 argmax (and of every tied code) always qualifies;
// exact fp32 rescore + (8191-code) key = numpy lowest-index tie-break.
//
// Outputs (float32, concatenated):
//   [0 .. 262144)        z_q_out [B,C,H,W]
//   [262144]             loss (scalar)
//   [262145 .. 270337)   token_ids [B,H,W] as float
//   [270337 .. 532481)   new_embedding [K,C]
//   [532481 .. 540673)   new_cluster_sizes [K]

#define NTOK   8192
#define NCODE  8192
#define CDIM   32
#define HW     256
#define DECAYF 0.99f
#define EPSF   0.01f

#define OUT_ZQ   0
#define OUT_LOSS 262144
#define OUT_IDS  262145
#define OUT_EMB  270337
#define OUT_CS   532481

// workspace byte offsets
#define WS_ZN     0u        // zn row-major [N,C] f32   = 1048576
#define WS_ZNBF   1048576u  // bf16 [N,C]               = 524288
#define WS_EBF    1572864u  // bf16 [K,C]               = 524288
#define WS_PMAX   2097152u  // f32 [32][N]              = 1048576
#define WS_BINS   3145728u  // i32 [K]                  = 32768  <- zeroed
#define WS_LOSSP  3178496u  // f32 [64]                 = 256
#define WS_ZEND   3178752u
#define WS_ZERO_BYTES (WS_ZEND - WS_BINS)
#define WS_IDS    3178752u  // i32 [N]
#define WS_POS    3211520u  // i32 [N]
#define WS_OFFS   3244288u  // i32 [K]
#define WS_SORTED 3277056u  // i32 [N]   (end 3309824 < ws floor)

#define CHUNK  256
#define NCHUNK (NCODE / CHUNK)  // 32
#define TILES  (CHUNK / 16)     // 16

typedef __attribute__((ext_vector_type(8))) short bf16x8;
typedef __attribute__((ext_vector_type(4))) float f32x4;

__device__ inline unsigned short f2bf(float x) {
    unsigned u = __float_as_uint(x);
    return (unsigned short)((u + 0x7FFFu + ((u >> 16) & 1u)) >> 16);
}
__device__ inline unsigned fmap(float s) {   // monotonic f32 -> u32
    unsigned u = __float_as_uint(s);
    return (u & 0x80000000u) ? ~u : (u | 0x80000000u);
}

// -------- Kernel A: blocks 0..31 token norm (zn + znbf); 32..159 emb -> ebf ----
__global__ __launch_bounds__(256) void k_prep(const float* __restrict__ z,
                                              const float* __restrict__ emb,
                                              float* __restrict__ zn,
                                              unsigned short* __restrict__ znbf,
                                              unsigned short* __restrict__ ebf) {
    if (blockIdx.x < 32) {
        int n = blockIdx.x * 256 + threadIdx.x;   // token = b*256 + hw
        int b = n >> 8, hw = n & 255;
        const float* zp = z + (size_t)b * (CDIM * HW) + hw;
        float v[CDIM];
        float ss = 0.f;
#pragma unroll
        for (int c = 0; c < CDIM; ++c) {
            float t = zp[c * HW];                 // coalesced per c
            v[c] = t;
            ss += t * t;
        }
        float d = fmaxf(sqrtf(ss), 1e-12f);
        float* o = zn + (size_t)n * CDIM;
        unsigned short* ob = znbf + (size_t)n * CDIM;
#pragma unroll
        for (int c = 0; c < CDIM; ++c) {
            float t = v[c] / d;
            o[c] = t;
            ob[c] = f2bf(t);
        }
    } else {
        int base = (blockIdx.x - 32) * 2048 + threadIdx.x * 8;
        const float4* s = (const float4*)(emb + base);
        float4 x = s[0], y = s[1];
        ushort4 u0 = {f2bf(x.x), f2bf(x.y), f2bf(x.z), f2bf(x.w)};
        ushort4 u1 = {f2bf(y.x), f2bf(y.y), f2bf(y.z), f2bf(y.w)};
        *(ushort4*)(ebf + base) = u0;
        *(ushort4*)(ebf + base + 4) = u1;
    }
}

// -------- Kernel B: MFMA scan -> pmax[chunk][tok] (no conversions, no atomics) --
__global__ __launch_bounds__(256) void k_max(const unsigned short* __restrict__ znbf,
                                             const unsigned short* __restrict__ ebf,
                                             float* __restrict__ pmax) {
    __shared__ unsigned short lbs[CHUNK * CDIM];  // 16 KiB
    __shared__ float lmax[256];
    int kbase = blockIdx.y * CHUNK;
    {   // stage bf16 chunk: 16 KiB, 64 B/thread
        const float4* src = (const float4*)(ebf + (size_t)kbase * CDIM);
        float4* dst = (float4*)lbs;
#pragma unroll
        for (int j = 0; j < 4; ++j)
            dst[threadIdx.x + j * 256] = src[threadIdx.x + j * 256];
    }
    __syncthreads();

    int wave = threadIdx.x >> 6, lane = threadIdx.x & 63;
    int col = lane & 15, quad = lane >> 4;
    int wtok = blockIdx.x * 256 + wave * 64;

    bf16x8 a[4];                                  // 4 frags = 64 tokens
#pragma unroll
    for (int f = 0; f < 4; ++f)
        a[f] = *(const bf16x8*)(znbf + (size_t)(wtok + f * 16 + col) * CDIM + quad * 8);

    const bf16x8* bl = (const bf16x8*)lbs;
    const f32x4 zero4 = {0.f, 0.f, 0.f, 0.f};
    float m[4][4];
#pragma unroll
    for (int f = 0; f < 4; ++f)
#pragma unroll
        for (int r = 0; r < 4; ++r) m[f][r] = -1e30f;

    for (int t = 0; t < TILES; ++t) {
        bf16x8 b = bl[(t * 16 + col) * 4 + quad];
#pragma unroll
        for (int f = 0; f < 4; ++f) {
            f32x4 d = __builtin_amdgcn_mfma_f32_16x16x32_bf16(a[f], b, zero4, 0, 0, 0);
#pragma unroll
            for (int r = 0; r < 4; ++r) m[f][r] = fmaxf(m[f][r], d[r]);
        }
    }
#pragma unroll
    for (int f = 0; f < 4; ++f)
#pragma unroll
        for (int r = 0; r < 4; ++r) {
            float v = m[f][r];
#pragma unroll
            for (int s = 1; s < 16; s <<= 1) v = fmaxf(v, __shfl_xor(v, s));
            if (col == 0) lmax[wave * 64 + f * 16 + quad * 4 + r] = v;
        }
    __syncthreads();
    pmax[(size_t)blockIdx.y * NTOK + blockIdx.x * 256 + threadIdx.x] = lmax[threadIdx.x];
}

// -------- Kernel C: half-wave per token gmax + exact rescore (barrier-free) ----
// 1024 blocks x 256 thr: wave = 2 tokens, half-wave (32 lanes) = 1 token.
__global__ __launch_bounds__(256) void k_pick2(const float* __restrict__ pmax,
                                               const float* __restrict__ zn,
                                               const float* __restrict__ emb,
                                               int* __restrict__ bins,
                                               int* __restrict__ ids,
                                               int* __restrict__ pos,
                                               float* __restrict__ out) {
    int wave = threadIdx.x >> 6, lane = threadIdx.x & 63;
    int half = lane >> 5, sub = lane & 31;
    int tok = blockIdx.x * 8 + wave * 2 + half;

    // per-token chunk maxima: lane sub reads chunk sub's partial
    float pm = pmax[(size_t)sub * NTOK + tok];
    float mx = pm;
#pragma unroll
    for (int s = 1; s < 32; s <<= 1)              // xor<32: stays in half
        mx = fmaxf(mx, __shfl_xor(mx, s));
    float thr = mx - EPSF;
    unsigned long long bal = __ballot(pm >= thr);
    unsigned qmask = (unsigned)(bal >> (half * 32));  // uniform within half

    // token's zn row in registers (hoisted; L1-broadcast across the half)
    const float4* zr = (const float4*)(zn + (size_t)tok * CDIM);
    float zp[CDIM];
#pragma unroll
    for (int j = 0; j < 8; ++j) {
        float4 q = zr[j];
        zp[4 * j + 0] = q.x; zp[4 * j + 1] = q.y;
        zp[4 * j + 2] = q.z; zp[4 * j + 3] = q.w;
    }

    unsigned long long bestkey = 0;
    while (qmask) {                               // ~1.05 iterations
        int ch = __ffs(qmask) - 1;
        qmask &= qmask - 1;
        int code0 = ch * 256 + sub * 8;           // 8 consecutive codes/lane
        const float* ep = emb + (size_t)code0 * CDIM;
#pragma unroll
        for (int k = 0; k < 8; ++k) {
            float a0 = 0.f, a1 = 0.f, a2 = 0.f, a3 = 0.f;
#pragma unroll
            for (int j = 0; j < 8; ++j) {
                a0 = __builtin_fmaf(zp[4 * j + 0], ep[4 * j + 0], a0);
                a1 = __builtin_fmaf(zp[4 * j + 1], ep[4 * j + 1], a1);
                a2 = __builtin_fmaf(zp[4 * j + 2], ep[4 * j + 2], a2);
                a3 = __builtin_fmaf(zp[4 * j + 3], ep[4 * j + 3], a3);
            }
            float s = (a0 + a1) + (a2 + a3);
            unsigned long long key = ((unsigned long long)fmap(s) << 13) |
                                     (unsigned long long)(8191 - (code0 + k));
            if (key > bestkey) bestkey = key;
            ep += CDIM;
        }
    }
    // half-wave u64 max reduce
#pragma unroll
    for (int s = 1; s < 32; s <<= 1) {
        unsigned long long o = __shfl_xor(bestkey, s);
        if (o > bestkey) bestkey = o;
    }
    if (sub == 0) {
        int id = 8191 - (int)(bestkey & 8191ull);
        ids[tok] = id;
        out[OUT_IDS + tok] = (float)id;
        pos[tok] = atomicAdd(bins + id, 1);       // 8192 scattered atomics total
    }
}

// -------- Kernel D: z_q gather + transpose-out + loss partials -----------------
// block = (b, c) pair: 1024 blocks x 256 hw-threads.
__global__ __launch_bounds__(256) void k_zq(const int* __restrict__ ids,
                                            const float* __restrict__ zn,
                                            const float* __restrict__ emb,
                                            float* __restrict__ out,
                                            float* __restrict__ loss_part) {
    __shared__ float lsum[4];
    int b = blockIdx.x >> 5, c = blockIdx.x & 31;
    int hw = threadIdx.x;
    int n = b * 256 + hw;
    int id = ids[n];
    float ev = emb[(size_t)id * CDIM + c];        // gather (L2)
    float zv = zn[(size_t)n * CDIM + c];          // 128B-stride (L2)
    out[OUT_ZQ + ((size_t)b * CDIM + c) * HW + hw] = ev;  // coalesced
    float dd = ev - zv;
    float s = dd * dd;
#pragma unroll
    for (int off = 32; off > 0; off >>= 1) s += __shfl_down(s, off);
    if ((hw & 63) == 0) lsum[hw >> 6] = s;
    __syncthreads();
    if (hw == 0)
        atomicAdd(loss_part + (blockIdx.x & 63),
                  lsum[0] + lsum[1] + lsum[2] + lsum[3]);
}

// -------- Kernel S: single-block scan of bins (wave-shuffle) + place sorted ----
__global__ __launch_bounds__(1024) void k_scanplace(const int* __restrict__ bins,
                                                    const int* __restrict__ ids,
                                                    const int* __restrict__ pos,
                                                    int* __restrict__ offs,
                                                    int* __restrict__ sorted) {
    __shared__ int wtot[16], wexcl[16];
    int t = threadIdx.x;
    int lane = t & 63, wid = t >> 6;
    int loc[8];
    int s = 0;
#pragma unroll
    for (int i = 0; i < 8; ++i) {                 // local exclusive prefix
        loc[i] = s;
        s += bins[t * 8 + i];
    }
    int v = s;                                    // wave-inclusive scan
#pragma unroll
    for (int sh = 1; sh < 64; sh <<= 1) {
        int o = __shfl_up(v, sh);
        if (lane >= sh) v += o;
    }
    if (lane == 63) wtot[wid] = v;
    __syncthreads();
    if (t < 16) {                                 // scan 16 wave totals
        int w = wtot[t];
        int iv = w;
#pragma unroll
        for (int sh = 1; sh < 16; sh <<= 1) {
            int o = __shfl_up(iv, sh);
            if (t >= sh) iv += o;
        }
        wexcl[t] = iv - w;
    }
    __syncthreads();
    int excl = wexcl[wid] + (v - s);              // global exclusive for thread
#pragma unroll
    for (int i = 0; i < 8; ++i) offs[t * 8 + i] = excl + loc[i];
    __syncthreads();
    for (int n = t; n < NTOK; n += 1024)
        sorted[offs[ids[n]] + pos[n]] = n;
}

// -------- Kernel F: EMA update via segment gather + renormalize + loss ---------
__global__ __launch_bounds__(256) void k_update(const float* __restrict__ zn,
                                                const float* __restrict__ emb,
                                                const float* __restrict__ cs,
                                                const int* __restrict__ bins,
                                                const int* __restrict__ offs,
                                                const int* __restrict__ sorted,
                                                const float* __restrict__ loss_part,
                                                float* __restrict__ out) {
    int idx = blockIdx.x * 256 + threadIdx.x;
    if (blockIdx.x == 0 && threadIdx.x < 64) {    // loss finalize (wave 0)
        float lp = loss_part[threadIdx.x];
#pragma unroll
        for (int sh = 32; sh > 0; sh >>= 1) lp += __shfl_down(lp, sh);
        if (threadIdx.x == 0) out[OUT_LOSS] = lp * (1.0f / 262144.0f);
    }
    int k = idx >> 5, c = idx & 31;
    int bi = bins[k];
    int off = offs[k];
    float t = 0.f;
    for (int i = 0; i < bi; ++i) {                // avg 1 iter
        int n = sorted[off + i];
        t += zn[(size_t)n * CDIM + c];            // coalesced 128B row
    }
    float bf = (float)bi;
    bool zero = (bi == 0);
    t /= (zero ? 1.0f : bf);
    float ss = t * t;
#pragma unroll
    for (int s = 1; s < 32; s <<= 1) ss += __shfl_xor(ss, s);
    float d = fmaxf(sqrtf(ss), 1e-12f);
    float ew = emb[idx];
    float en = zero ? ew : (t / d);
    float w = ew * DECAYF + (1.0f - DECAYF) * en;
    float ss2 = w * w;
#pragma unroll
    for (int s = 1; s < 32; s <<= 1) ss2 += __shfl_xor(ss2, s);
    float d2 = fmaxf(sqrtf(ss2), 1e-12f);
    out[OUT_EMB + idx] = w / d2;
    if (c == 0) out[OUT_CS + k] = cs[k] * DECAYF + (1.0f - DECAYF) * bf;
}

extern "C" void kernel_launch(void* const* d_in, const int* in_sizes, int n_in,
                              void* d_out, int out_size, void* d_ws, size_t ws_size,
                              hipStream_t stream) {
    const float* z   = (const float*)d_in[0];   // [32,32,16,16]
    const float* emb = (const float*)d_in[1];   // [8192,32]
    const float* cs  = (const float*)d_in[2];   // [8192]
    float* out = (float*)d_out;
    char* ws = (char*)d_ws;

    float* zn            = (float*)(ws + WS_ZN);
    unsigned short* znbf = (unsigned short*)(ws + WS_ZNBF);
    unsigned short* ebf  = (unsigned short*)(ws + WS_EBF);
    float* pmax          = (float*)(ws + WS_PMAX);
    int* bins            = (int*)(ws + WS_BINS);
    float* loss_part     = (float*)(ws + WS_LOSSP);
    int* ids             = (int*)(ws + WS_IDS);
    int* pos             = (int*)(ws + WS_POS);
    int* offs            = (int*)(ws + WS_OFFS);
    int* sorted          = (int*)(ws + WS_SORTED);

    hipMemsetAsync(ws + WS_BINS, 0, WS_ZERO_BYTES, stream);

    k_prep<<<dim3(160), 256, 0, stream>>>(z, emb, zn, znbf, ebf);
    k_max<<<dim3(NTOK / 256, NCHUNK), 256, 0, stream>>>(znbf, ebf, pmax);
    k_pick2<<<dim3(NTOK / 8), 256, 0, stream>>>(pmax, zn, emb, bins, ids, pos, out);
    k_zq<<<dim3(1024), 256, 0, stream>>>(ids, zn, emb, out, loss_part);
    k_scanplace<<<dim3(1), 1024, 0, stream>>>(bins, ids, pos, offs, sorted);
    k_update<<<dim3(1024), 256, 0, stream>>>(zn, emb, cs, bins, offs, sorted, loss_part, out);
}

// Round 11
// 185.937 us; speedup vs baseline: 1.1466x; 1.1466x over previous
//
#include <hip/hip_runtime.h>

// NormEMAVectorQuantizer on MI355X (gfx950)
// N=8192 tokens, C=32, K=8192 codes, B=32, H*W=256.
// R11 = R10 with two fixes: (a) k_pick2 rescore loop #pragma unroll 1 +
// __launch_bounds__(256,4) — R10's full unroll hit 240 VGPR -> 2 waves/SIMD
// (7.5% occupancy, 104us); (b) pmax stored TRANSPOSED [tok][chunk] so a
// token's 32 chunk maxima are one 128B cache line (R10 gathered 32 lines).
// Certificate: bf16 dot err <= 2*2^-9 = 0.0078 < eps=0.01 for unit rows, so
// the chunk of the fp32 argmax (and of every tied code) always qualifies;
// exact fp32 rescore + (8191-code) key = numpy lowest-index tie-break.
//
// Outputs (float32, concatenated):
//   [0 .. 262144)        z_q_out [B,C,H,W]
//   [262144]             loss (scalar)
//   [262145 .. 270337)   token_ids [B,H,W] as float
//   [270337 .. 532481)   new_embedding [K,C]
//   [532481 .. 540673)   new_cluster_sizes [K]

#define NTOK   8192
#define NCODE  8192
#define CDIM   32
#define HW     256
#define DECAYF 0.99f
#define EPSF   0.01f

#define OUT_ZQ   0
#define OUT_LOSS 262144
#define OUT_IDS  262145
#define OUT_EMB  270337
#define OUT_CS   532481

// workspace byte offsets
#define WS_ZN     0u        // zn row-major [N,C] f32   = 1048576
#define WS_ZNBF   1048576u  // bf16 [N,C]               = 524288
#define WS_EBF    1572864u  // bf16 [K,C]               = 524288
#define WS_PMAX   2097152u  // f32 [N][32] (TRANSPOSED) = 1048576
#define WS_BINS   3145728u  // i32 [K]                  = 32768  <- zeroed
#define WS_LOSSP  3178496u  // f32 [64]                 = 256
#define WS_ZEND   3178752u
#define WS_ZERO_BYTES (WS_ZEND - WS_BINS)
#define WS_IDS    3178752u  // i32 [N]
#define WS_POS    3211520u  // i32 [N]
#define WS_OFFS   3244288u  // i32 [K]
#define WS_SORTED 3277056u  // i32 [N]   (end 3309824 < ws floor)

#define CHUNK  256
#define NCHUNK (NCODE / CHUNK)  // 32
#define TILES  (CHUNK / 16)     // 16

typedef __attribute__((ext_vector_type(8))) short bf16x8;
typedef __attribute__((ext_vector_type(4))) float f32x4;

__device__ inline unsigned short f2bf(float x) {
    unsigned u = __float_as_uint(x);
    return (unsigned short)((u + 0x7FFFu + ((u >> 16) & 1u)) >> 16);
}
__device__ inline unsigned fmap(float s) {   // monotonic f32 -> u32
    unsigned u = __float_as_uint(s);
    return (u & 0x80000000u) ? ~u : (u | 0x80000000u);
}

// -------- Kernel A: blocks 0..31 token norm (zn + znbf); 32..159 emb -> ebf ----
__global__ __launch_bounds__(256) void k_prep(const float* __restrict__ z,
                                              const float* __restrict__ emb,
                                              float* __restrict__ zn,
                                              unsigned short* __restrict__ znbf,
                                              unsigned short* __restrict__ ebf) {
    if (blockIdx.x < 32) {
        int n = blockIdx.x * 256 + threadIdx.x;   // token = b*256 + hw
        int b = n >> 8, hw = n & 255;
        const float* zp = z + (size_t)b * (CDIM * HW) + hw;
        float v[CDIM];
        float ss = 0.f;
#pragma unroll
        for (int c = 0; c < CDIM; ++c) {
            float t = zp[c * HW];                 // coalesced per c
            v[c] = t;
            ss += t * t;
        }
        float d = fmaxf(sqrtf(ss), 1e-12f);
        float* o = zn + (size_t)n * CDIM;
        unsigned short* ob = znbf + (size_t)n * CDIM;
#pragma unroll
        for (int c = 0; c < CDIM; ++c) {
            float t = v[c] / d;
            o[c] = t;
            ob[c] = f2bf(t);
        }
    } else {
        int base = (blockIdx.x - 32) * 2048 + threadIdx.x * 8;
        const float4* s = (const float4*)(emb + base);
        float4 x = s[0], y = s[1];
        ushort4 u0 = {f2bf(x.x), f2bf(x.y), f2bf(x.z), f2bf(x.w)};
        ushort4 u1 = {f2bf(y.x), f2bf(y.y), f2bf(y.z), f2bf(y.w)};
        *(ushort4*)(ebf + base) = u0;
        *(ushort4*)(ebf + base + 4) = u1;
    }
}

// -------- Kernel B: MFMA scan -> pmaxT[tok][chunk] (transposed store) ----------
__global__ __launch_bounds__(256) void k_max(const unsigned short* __restrict__ znbf,
                                             const unsigned short* __restrict__ ebf,
                                             float* __restrict__ pmaxT) {
    __shared__ unsigned short lbs[CHUNK * CDIM];  // 16 KiB
    __shared__ float lmax[256];
    int kbase = blockIdx.y * CHUNK;
    {   // stage bf16 chunk: 16 KiB, 64 B/thread
        const float4* src = (const float4*)(ebf + (size_t)kbase * CDIM);
        float4* dst = (float4*)lbs;
#pragma unroll
        for (int j = 0; j < 4; ++j)
            dst[threadIdx.x + j * 256] = src[threadIdx.x + j * 256];
    }
    __syncthreads();

    int wave = threadIdx.x >> 6, lane = threadIdx.x & 63;
    int col = lane & 15, quad = lane >> 4;
    int wtok = blockIdx.x * 256 + wave * 64;

    bf16x8 a[4];                                  // 4 frags = 64 tokens
#pragma unroll
    for (int f = 0; f < 4; ++f)
        a[f] = *(const bf16x8*)(znbf + (size_t)(wtok + f * 16 + col) * CDIM + quad * 8);

    const bf16x8* bl = (const bf16x8*)lbs;
    const f32x4 zero4 = {0.f, 0.f, 0.f, 0.f};
    float m[4][4];
#pragma unroll
    for (int f = 0; f < 4; ++f)
#pragma unroll
        for (int r = 0; r < 4; ++r) m[f][r] = -1e30f;

    for (int t = 0; t < TILES; ++t) {
        bf16x8 b = bl[(t * 16 + col) * 4 + quad];
#pragma unroll
        for (int f = 0; f < 4; ++f) {
            f32x4 d = __builtin_amdgcn_mfma_f32_16x16x32_bf16(a[f], b, zero4, 0, 0, 0);
#pragma unroll
            for (int r = 0; r < 4; ++r) m[f][r] = fmaxf(m[f][r], d[r]);
        }
    }
#pragma unroll
    for (int f = 0; f < 4; ++f)
#pragma unroll
        for (int r = 0; r < 4; ++r) {
            float v = m[f][r];
#pragma unroll
            for (int s = 1; s < 16; s <<= 1) v = fmaxf(v, __shfl_xor(v, s));
            if (col == 0) lmax[wave * 64 + f * 16 + quad * 4 + r] = v;
        }
    __syncthreads();
    // transposed: token-major. 4B scatter-store, stride 128B (stores don't stall)
    pmaxT[(size_t)(blockIdx.x * 256 + threadIdx.x) * NCHUNK + blockIdx.y] =
        lmax[threadIdx.x];
}

// -------- Kernel C: half-wave per token gmax + exact rescore (barrier-free) ----
// 1024 blocks x 256 thr: wave = 2 tokens, half-wave (32 lanes) = 1 token.
// launch_bounds(256,4): cap VGPR <= 128 (grid gives 4 waves/SIMD; R10's full
// unroll hit 240 VGPR -> 2 waves/SIMD and 104us).
__global__ __launch_bounds__(256, 4) void k_pick2(const float* __restrict__ pmaxT,
                                                  const float* __restrict__ zn,
                                                  const float* __restrict__ emb,
                                                  int* __restrict__ bins,
                                                  int* __restrict__ ids,
                                                  int* __restrict__ pos,
                                                  float* __restrict__ out) {
    int wave = threadIdx.x >> 6, lane = threadIdx.x & 63;
    int half = lane >> 5, sub = lane & 31;
    int tok = blockIdx.x * 8 + wave * 2 + half;

    // token's 32 chunk maxima = one 128B line, coalesced across the half-wave
    float pm = pmaxT[(size_t)tok * NCHUNK + sub];
    float mx = pm;
#pragma unroll
    for (int s = 1; s < 32; s <<= 1)              // xor<32: stays in half
        mx = fmaxf(mx, __shfl_xor(mx, s));
    float thr = mx - EPSF;
    unsigned long long bal = __ballot(pm >= thr);
    unsigned qmask = (unsigned)(bal >> (half * 32));  // uniform within half

    // token's zn row in registers (L1-broadcast across the half)
    const float4* zr = (const float4*)(zn + (size_t)tok * CDIM);
    float zp[CDIM];
#pragma unroll
    for (int j = 0; j < 8; ++j) {
        float4 q = zr[j];
        zp[4 * j + 0] = q.x; zp[4 * j + 1] = q.y;
        zp[4 * j + 2] = q.z; zp[4 * j + 3] = q.w;
    }

    unsigned long long bestkey = 0;
    while (qmask) {                               // ~1.05 iterations
        int ch = __ffs(qmask) - 1;
        qmask &= qmask - 1;
        int code0 = ch * 256 + sub * 8;           // 8 consecutive codes/lane
#pragma unroll 1
        for (int k = 0; k < 8; ++k) {             // unroll 1: keep VGPR low
            const float4* ef = (const float4*)(emb + (size_t)(code0 + k) * CDIM);
            float4 e0 = ef[0], e1 = ef[1], e2 = ef[2], e3 = ef[3];
            float4 e4 = ef[4], e5 = ef[5], e6 = ef[6], e7 = ef[7];
            float a0 = zp[0] * e0.x, a1 = zp[1] * e0.y;
            float a2 = zp[2] * e0.z, a3 = zp[3] * e0.w;
            a0 = __builtin_fmaf(zp[4], e1.x, a0); a1 = __builtin_fmaf(zp[5], e1.y, a1);
            a2 = __builtin_fmaf(zp[6], e1.z, a2); a3 = __builtin_fmaf(zp[7], e1.w, a3);
            a0 = __builtin_fmaf(zp[8], e2.x, a0); a1 = __builtin_fmaf(zp[9], e2.y, a1);
            a2 = __builtin_fmaf(zp[10], e2.z, a2); a3 = __builtin_fmaf(zp[11], e2.w, a3);
            a0 = __builtin_fmaf(zp[12], e3.x, a0); a1 = __builtin_fmaf(zp[13], e3.y, a1);
            a2 = __builtin_fmaf(zp[14], e3.z, a2); a3 = __builtin_fmaf(zp[15], e3.w, a3);
            a0 = __builtin_fmaf(zp[16], e4.x, a0); a1 = __builtin_fmaf(zp[17], e4.y, a1);
            a2 = __builtin_fmaf(zp[18], e4.z, a2); a3 = __builtin_fmaf(zp[19], e4.w, a3);
            a0 = __builtin_fmaf(zp[20], e5.x, a0); a1 = __builtin_fmaf(zp[21], e5.y, a1);
            a2 = __builtin_fmaf(zp[22], e5.z, a2); a3 = __builtin_fmaf(zp[23], e5.w, a3);
            a0 = __builtin_fmaf(zp[24], e6.x, a0); a1 = __builtin_fmaf(zp[25], e6.y, a1);
            a2 = __builtin_fmaf(zp[26], e6.z, a2); a3 = __builtin_fmaf(zp[27], e6.w, a3);
            a0 = __builtin_fmaf(zp[28], e7.x, a0); a1 = __builtin_fmaf(zp[29], e7.y, a1);
            a2 = __builtin_fmaf(zp[30], e7.z, a2); a3 = __builtin_fmaf(zp[31], e7.w, a3);
            float s = (a0 + a1) + (a2 + a3);
            unsigned long long key = ((unsigned long long)fmap(s) << 13) |
                                     (unsigned long long)(8191 - (code0 + k));
            if (key > bestkey) bestkey = key;
        }
    }
    // half-wave u64 max reduce
#pragma unroll
    for (int s = 1; s < 32; s <<= 1) {
        unsigned long long o = __shfl_xor(bestkey, s);
        if (o > bestkey) bestkey = o;
    }
    if (sub == 0) {
        int id = 8191 - (int)(bestkey & 8191ull);
        ids[tok] = id;
        out[OUT_IDS + tok] = (float)id;
        pos[tok] = atomicAdd(bins + id, 1);       // 8192 scattered atomics total
    }
}

// -------- Kernel D: z_q gather + transpose-out + loss partials -----------------
// block = (b, c) pair: 1024 blocks x 256 hw-threads.
__global__ __launch_bounds__(256) void k_zq(const int* __restrict__ ids,
                                            const float* __restrict__ zn,
                                            const float* __restrict__ emb,
                                            float* __restrict__ out,
                                            float* __restrict__ loss_part) {
    __shared__ float lsum[4];
    int b = blockIdx.x >> 5, c = blockIdx.x & 31;
    int hw = threadIdx.x;
    int n = b * 256 + hw;
    int id = ids[n];
    float ev = emb[(size_t)id * CDIM + c];        // gather (L2)
    float zv = zn[(size_t)n * CDIM + c];          // 128B-stride (L2)
    out[OUT_ZQ + ((size_t)b * CDIM + c) * HW + hw] = ev;  // coalesced
    float dd = ev - zv;
    float s = dd * dd;
#pragma unroll
    for (int off = 32; off > 0; off >>= 1) s += __shfl_down(s, off);
    if ((hw & 63) == 0) lsum[hw >> 6] = s;
    __syncthreads();
    if (hw == 0)
        atomicAdd(loss_part + (blockIdx.x & 63),
                  lsum[0] + lsum[1] + lsum[2] + lsum[3]);
}

// -------- Kernel S: single-block scan of bins (wave-shuffle) + place sorted ----
__global__ __launch_bounds__(1024) void k_scanplace(const int* __restrict__ bins,
                                                    const int* __restrict__ ids,
                                                    const int* __restrict__ pos,
                                                    int* __restrict__ offs,
                                                    int* __restrict__ sorted) {
    __shared__ int wtot[16], wexcl[16];
    int t = threadIdx.x;
    int lane = t & 63, wid = t >> 6;
    int loc[8];
    int s = 0;
#pragma unroll
    for (int i = 0; i < 8; ++i) {                 // local exclusive prefix
        loc[i] = s;
        s += bins[t * 8 + i];
    }
    int v = s;                                    // wave-inclusive scan
#pragma unroll
    for (int sh = 1; sh < 64; sh <<= 1) {
        int o = __shfl_up(v, sh);
        if (lane >= sh) v += o;
    }
    if (lane == 63) wtot[wid] = v;
    __syncthreads();
    if (t < 16) {                                 // scan 16 wave totals
        int w = wtot[t];
        int iv = w;
#pragma unroll
        for (int sh = 1; sh < 16; sh <<= 1) {
            int o = __shfl_up(iv, sh);
            if (t >= sh) iv += o;
        }
        wexcl[t] = iv - w;
    }
    __syncthreads();
    int excl = wexcl[wid] + (v - s);              // global exclusive for thread
#pragma unroll
    for (int i = 0; i < 8; ++i) offs[t * 8 + i] = excl + loc[i];
    __syncthreads();
    for (int n = t; n < NTOK; n += 1024)
        sorted[offs[ids[n]] + pos[n]] = n;
}

// -------- Kernel F: EMA update via segment gather + renormalize + loss ---------
__global__ __launch_bounds__(256) void k_update(const float* __restrict__ zn,
                                                const float* __restrict__ emb,
                                                const float* __restrict__ cs,
                                                const int* __restrict__ bins,
                                                const int* __restrict__ offs,
                                                const int* __restrict__ sorted,
                                                const float* __restrict__ loss_part,
                                                float* __restrict__ out) {
    int idx = blockIdx.x * 256 + threadIdx.x;
    if (blockIdx.x == 0 && threadIdx.x < 64) {    // loss finalize (wave 0)
        float lp = loss_part[threadIdx.x];
#pragma unroll
        for (int sh = 32; sh > 0; sh >>= 1) lp += __shfl_down(lp, sh);
        if (threadIdx.x == 0) out[OUT_LOSS] = lp * (1.0f / 262144.0f);
    }
    int k = idx >> 5, c = idx & 31;
    int bi = bins[k];
    int off = offs[k];
    float t = 0.f;
    for (int i = 0; i < bi; ++i) {                // avg 1 iter
        int n = sorted[off + i];
        t += zn[(size_t)n * CDIM + c];            // coalesced 128B row
    }
    float bf = (float)bi;
    bool zero = (bi == 0);
    t /= (zero ? 1.0f : bf);
    float ss = t * t;
#pragma unroll
    for (int s = 1; s < 32; s <<= 1) ss += __shfl_xor(ss, s);
    float d = fmaxf(sqrtf(ss), 1e-12f);
    float ew = emb[idx];
    float en = zero ? ew : (t / d);
    float w = ew * DECAYF + (1.0f - DECAYF) * en;
    float ss2 = w * w;
#pragma unroll
    for (int s = 1; s < 32; s <<= 1) ss2 += __shfl_xor(ss2, s);
    float d2 = fmaxf(sqrtf(ss2), 1e-12f);
    out[OUT_EMB + idx] = w / d2;
    if (c == 0) out[OUT_CS + k] = cs[k] * DECAYF + (1.0f - DECAYF) * bf;
}

extern "C" void kernel_launch(void* const* d_in, const int* in_sizes, int n_in,
                              void* d_out, int out_size, void* d_ws, size_t ws_size,
                              hipStream_t stream) {
    const float* z   = (const float*)d_in[0];   // [32,32,16,16]
    const float* emb = (const float*)d_in[1];   // [8192,32]
    const float* cs  = (const float*)d_in[2];   // [8192]
    float* out = (float*)d_out;
    char* ws = (char*)d_ws;

    float* zn            = (float*)(ws + WS_ZN);
    unsigned short* znbf = (unsigned short*)(ws + WS_ZNBF);
    unsigned short* ebf  = (unsigned short*)(ws + WS_EBF);
    float* pmaxT         = (float*)(ws + WS_PMAX);
    int* bins            = (int*)(ws + WS_BINS);
    float* loss_part     = (float*)(ws + WS_LOSSP);
    int* ids             = (int*)(ws + WS_IDS);
    int* pos             = (int*)(ws + WS_POS);
    int* offs            = (int*)(ws + WS_OFFS);
    int* sorted          = (int*)(ws + WS_SORTED);

    hipMemsetAsync(ws + WS_BINS, 0, WS_ZERO_BYTES, stream);

    k_prep<<<dim3(160), 256, 0, stream>>>(z, emb, zn, znbf, ebf);
    k_max<<<dim3(NTOK / 256, NCHUNK), 256, 0, stream>>>(znbf, ebf, pmaxT);
    k_pick2<<<dim3(NTOK / 8), 256, 0, stream>>>(pmaxT, zn, emb, bins, ids, pos, out);
    k_zq<<<dim3(1024), 256, 0, stream>>>(ids, zn, emb, out, loss_part);
    k_scanplace<<<dim3(1), 1024, 0, stream>>>(bins, ids, pos, offs, sorted);
    k_update<<<dim3(1024), 256, 0, stream>>>(zn, emb, cs, bins, offs, sorted, loss_part, out);
}

// Round 12
// 132.424 us; speedup vs baseline: 1.6099x; 1.4041x over previous
//
#include <hip/hip_runtime.h>

// NormEMAVectorQuantizer on MI355X (gfx950)
// N=8192 tokens, C=32, K=8192 codes, B=32, H*W=256.
// R12 = R7's dense two-sweep structure (best total so far, 146us) with bf16
// PRE-CONVERTED once in k_prep (R7 re-converted fp32->bf16 inline in BOTH
// sweeps, ~300 VALU inst/thread each). Sparse pass-2 variants (R8-R11,
// 42-104us) all lost to R7's dense MFMA rescan: per-lane emb-row gathers
// put 64 distinct cache lines under every load instruction and thrash L1;
// dense LDS-staged MFMA is the pattern this HW eats. Pass 2 stays dense.
// Certificate: bf16 dot err <= 2*2^-9 = 0.0078 < eps=0.01 for unit rows, so
// every code that can be the fp32 argmax (incl. all ties) has bf16 score >=
// gmax-eps and is exact-rescored in fp32; (8191-code) key = numpy tie-break.
//
// Outputs (float32, concatenated):
//   [0 .. 262144)        z_q_out [B,C,H,W]
//   [262144]             loss (scalar)
//   [262145 .. 270337)   token_ids [B,H,W] as float
//   [270337 .. 532481)   new_embedding [K,C]
//   [532481 .. 540673)   new_cluster_sizes [K]

#define NTOK   8192
#define NCODE  8192
#define CDIM   32
#define HW     256
#define DECAYF 0.99f
#define EPSF   0.01f

#define OUT_ZQ   0
#define OUT_LOSS 262144
#define OUT_IDS  262145
#define OUT_EMB  270337
#define OUT_CS   532481

// workspace byte offsets
#define WS_ZN     0u        // zn row-major [N,C] f32   = 1048576
#define WS_ZNBF   1048576u  // bf16 [N,C]               = 524288
#define WS_EBF    1572864u  // bf16 [K,C]               = 524288
#define WS_PMAX   2097152u  // f32 [32][N]              = 1048576
#define WS_PACK   3145728u  // u64 [N]                  = 65536  <- zeroed
#define WS_BINS   3211264u  // i32 [K]                  = 32768
#define WS_LOSSP  3244032u  // f32 [64]                 = 256
#define WS_ZEND   3244288u
#define WS_ZERO_BYTES (WS_ZEND - WS_PACK)
#define WS_IDS    3244288u  // i32 [N]
#define WS_POS    3277056u  // i32 [N]
#define WS_OFFS   3309824u  // i32 [K]
#define WS_SORTED 3342592u  // i32 [N]  (end 3375360, under proven ws floor)

#define CHUNK  256
#define NCHUNK (NCODE / CHUNK)  // 32
#define TILES  (CHUNK / 16)     // 16

typedef __attribute__((ext_vector_type(8))) short bf16x8;
typedef __attribute__((ext_vector_type(4))) float f32x4;

__device__ inline unsigned short f2bf(float x) {
    unsigned u = __float_as_uint(x);
    return (unsigned short)((u + 0x7FFFu + ((u >> 16) & 1u)) >> 16);
}
__device__ inline unsigned fmap(float s) {   // monotonic f32 -> u32
    unsigned u = __float_as_uint(s);
    return (u & 0x80000000u) ? ~u : (u | 0x80000000u);
}

// -------- Kernel A: blocks 0..31 token norm (zn + znbf); 32..159 emb -> ebf ----
__global__ __launch_bounds__(256) void k_prep(const float* __restrict__ z,
                                              const float* __restrict__ emb,
                                              float* __restrict__ zn,
                                              unsigned short* __restrict__ znbf,
                                              unsigned short* __restrict__ ebf) {
    if (blockIdx.x < 32) {
        int n = blockIdx.x * 256 + threadIdx.x;   // token = b*256 + hw
        int b = n >> 8, hw = n & 255;
        const float* zp = z + (size_t)b * (CDIM * HW) + hw;
        float v[CDIM];
        float ss = 0.f;
#pragma unroll
        for (int c = 0; c < CDIM; ++c) {
            float t = zp[c * HW];                 // coalesced per c
            v[c] = t;
            ss += t * t;
        }
        float d = fmaxf(sqrtf(ss), 1e-12f);
        float* o = zn + (size_t)n * CDIM;
        unsigned short* ob = znbf + (size_t)n * CDIM;
#pragma unroll
        for (int c = 0; c < CDIM; ++c) {
            float t = v[c] / d;
            o[c] = t;
            ob[c] = f2bf(t);
        }
    } else {
        int base = (blockIdx.x - 32) * 2048 + threadIdx.x * 8;
        const float4* s = (const float4*)(emb + base);
        float4 x = s[0], y = s[1];
        ushort4 u0 = {f2bf(x.x), f2bf(x.y), f2bf(x.z), f2bf(x.w)};
        ushort4 u1 = {f2bf(y.x), f2bf(y.y), f2bf(y.z), f2bf(y.w)};
        *(ushort4*)(ebf + base) = u0;
        *(ushort4*)(ebf + base + 4) = u1;
    }
}

// -------- Kernel B: MFMA scan -> pmax[chunk][tok] (preconverted bf16) ----------
__global__ __launch_bounds__(256) void k_max(const unsigned short* __restrict__ znbf,
                                             const unsigned short* __restrict__ ebf,
                                             float* __restrict__ pmax) {
    __shared__ unsigned short lbs[CHUNK * CDIM];  // 16 KiB
    __shared__ float lmax[256];
    int kbase = blockIdx.y * CHUNK;
    {   // stage bf16 chunk: 16 KiB, 64 B/thread
        const float4* src = (const float4*)(ebf + (size_t)kbase * CDIM);
        float4* dst = (float4*)lbs;
#pragma unroll
        for (int j = 0; j < 4; ++j)
            dst[threadIdx.x + j * 256] = src[threadIdx.x + j * 256];
    }
    __syncthreads();

    int wave = threadIdx.x >> 6, lane = threadIdx.x & 63;
    int col = lane & 15, quad = lane >> 4;
    int wtok = blockIdx.x * 256 + wave * 64;

    bf16x8 a[4];                                  // 4 frags = 64 tokens
#pragma unroll
    for (int f = 0; f < 4; ++f)
        a[f] = *(const bf16x8*)(znbf + (size_t)(wtok + f * 16 + col) * CDIM + quad * 8);

    const bf16x8* bl = (const bf16x8*)lbs;
    const f32x4 zero4 = {0.f, 0.f, 0.f, 0.f};
    float m[4][4];
#pragma unroll
    for (int f = 0; f < 4; ++f)
#pragma unroll
        for (int r = 0; r < 4; ++r) m[f][r] = -1e30f;

    for (int t = 0; t < TILES; ++t) {
        bf16x8 b = bl[(t * 16 + col) * 4 + quad];
#pragma unroll
        for (int f = 0; f < 4; ++f) {
            f32x4 d = __builtin_amdgcn_mfma_f32_16x16x32_bf16(a[f], b, zero4, 0, 0, 0);
#pragma unroll
            for (int r = 0; r < 4; ++r) m[f][r] = fmaxf(m[f][r], d[r]);
        }
    }
#pragma unroll
    for (int f = 0; f < 4; ++f)
#pragma unroll
        for (int r = 0; r < 4; ++r) {
            float v = m[f][r];
#pragma unroll
            for (int s = 1; s < 16; s <<= 1) v = fmaxf(v, __shfl_xor(v, s));
            if (col == 0) lmax[wave * 64 + f * 16 + quad * 4 + r] = v;
        }
    __syncthreads();
    pmax[(size_t)blockIdx.y * NTOK + blockIdx.x * 256 + threadIdx.x] = lmax[threadIdx.x];
}

// -------- Kernel C: DENSE MFMA rescan vs global threshold + inline fp32 rescore -
__global__ __launch_bounds__(256) void k_pick(const unsigned short* __restrict__ znbf,
                                              const unsigned short* __restrict__ ebf,
                                              const float* __restrict__ zn,
                                              const float* __restrict__ emb,
                                              const float* __restrict__ pmax,
                                              unsigned long long* __restrict__ packed) {
    __shared__ unsigned short lbs[CHUNK * CDIM];  // 16 KiB
    __shared__ float lthr[256];
    int kbase = blockIdx.y * CHUNK;
    {   // stage bf16 chunk
        const float4* src = (const float4*)(ebf + (size_t)kbase * CDIM);
        float4* dst = (float4*)lbs;
#pragma unroll
        for (int j = 0; j < 4; ++j)
            dst[threadIdx.x + j * 256] = src[threadIdx.x + j * 256];
    }
    {   // per-token global threshold: 32 coalesced loads
        int tok = blockIdx.x * 256 + threadIdx.x;
        float mx = -1e30f;
#pragma unroll
        for (int ch = 0; ch < NCHUNK; ++ch)
            mx = fmaxf(mx, pmax[(size_t)ch * NTOK + tok]);
        lthr[threadIdx.x] = mx - EPSF;
    }
    __syncthreads();

    int wave = threadIdx.x >> 6, lane = threadIdx.x & 63;
    int col = lane & 15, quad = lane >> 4;
    int wtok = blockIdx.x * 256 + wave * 64;

    bf16x8 a[4];
#pragma unroll
    for (int f = 0; f < 4; ++f)
        a[f] = *(const bf16x8*)(znbf + (size_t)(wtok + f * 16 + col) * CDIM + quad * 8);

    float thr[4][4];
#pragma unroll
    for (int f = 0; f < 4; ++f)
#pragma unroll
        for (int r = 0; r < 4; ++r)
            thr[f][r] = lthr[wave * 64 + f * 16 + quad * 4 + r];

    const bf16x8* bl = (const bf16x8*)lbs;
    const f32x4 zero4 = {0.f, 0.f, 0.f, 0.f};

    for (int t = 0; t < TILES; ++t) {
        bf16x8 b = bl[(t * 16 + col) * 4 + quad];
#pragma unroll
        for (int f = 0; f < 4; ++f) {
            f32x4 d = __builtin_amdgcn_mfma_f32_16x16x32_bf16(a[f], b, zero4, 0, 0, 0);
#pragma unroll
            for (int r = 0; r < 4; ++r) {
                if (d[r] >= thr[f][r]) {          // rare: ~1.05/token total
                    int tok = wtok + f * 16 + quad * 4 + r;
                    int code = kbase + t * 16 + col;
                    const float* zp = zn + (size_t)tok * CDIM;
                    const float* ep = emb + (size_t)code * CDIM;
                    float a0 = 0.f, a1 = 0.f, a2 = 0.f, a3 = 0.f;
#pragma unroll
                    for (int j = 0; j < 8; ++j) {
                        a0 = __builtin_fmaf(zp[4 * j + 0], ep[4 * j + 0], a0);
                        a1 = __builtin_fmaf(zp[4 * j + 1], ep[4 * j + 1], a1);
                        a2 = __builtin_fmaf(zp[4 * j + 2], ep[4 * j + 2], a2);
                        a3 = __builtin_fmaf(zp[4 * j + 3], ep[4 * j + 3], a3);
                    }
                    float s = (a0 + a1) + (a2 + a3);
                    atomicMax(packed + tok, ((unsigned long long)fmap(s) << 13) |
                                            (unsigned long long)(8191 - code));
                }
            }
        }
    }
}

// -------- Kernel D: blocks 0..1023 = z_q gather + loss; 1024..1055 = ids/pos ---
__global__ __launch_bounds__(256) void k_postzq(const unsigned long long* __restrict__ packed,
                                                const float* __restrict__ zn,
                                                const float* __restrict__ emb,
                                                int* __restrict__ bins,
                                                int* __restrict__ ids,
                                                int* __restrict__ pos,
                                                float* __restrict__ out,
                                                float* __restrict__ loss_part) {
    if (blockIdx.x >= 1024) {                     // token per thread
        int n = (blockIdx.x - 1024) * 256 + threadIdx.x;
        int id = 8191 - (int)(packed[n] & 8191ull);
        ids[n] = id;
        out[OUT_IDS + n] = (float)id;
        pos[n] = atomicAdd(bins + id, 1);         // 8192 scattered atomics
        return;
    }
    __shared__ float lsum[4];
    int b = blockIdx.x >> 5, c = blockIdx.x & 31;
    int hw = threadIdx.x;
    int n = b * 256 + hw;
    int id = 8191 - (int)(packed[n] & 8191ull);
    float ev = emb[(size_t)id * CDIM + c];        // gather (L2)
    float zv = zn[(size_t)n * CDIM + c];          // 128B-stride (L2)
    out[OUT_ZQ + ((size_t)b * CDIM + c) * HW + hw] = ev;  // coalesced
    float dd = ev - zv;
    float s = dd * dd;
#pragma unroll
    for (int off = 32; off > 0; off >>= 1) s += __shfl_down(s, off);
    if ((hw & 63) == 0) lsum[hw >> 6] = s;
    __syncthreads();
    if (hw == 0)
        atomicAdd(loss_part + (blockIdx.x & 63),
                  lsum[0] + lsum[1] + lsum[2] + lsum[3]);
}

// -------- Kernel S: single-block scan of bins (wave-shuffle) + place sorted ----
__global__ __launch_bounds__(1024) void k_scanplace(const int* __restrict__ bins,
                                                    const int* __restrict__ ids,
                                                    const int* __restrict__ pos,
                                                    int* __restrict__ offs,
                                                    int* __restrict__ sorted) {
    __shared__ int wtot[16], wexcl[16];
    int t = threadIdx.x;
    int lane = t & 63, wid = t >> 6;
    int loc[8];
    int s = 0;
#pragma unroll
    for (int i = 0; i < 8; ++i) {                 // local exclusive prefix
        loc[i] = s;
        s += bins[t * 8 + i];
    }
    int v = s;                                    // wave-inclusive scan
#pragma unroll
    for (int sh = 1; sh < 64; sh <<= 1) {
        int o = __shfl_up(v, sh);
        if (lane >= sh) v += o;
    }
    if (lane == 63) wtot[wid] = v;
    __syncthreads();
    if (t < 16) {                                 // scan 16 wave totals
        int w = wtot[t];
        int iv = w;
#pragma unroll
        for (int sh = 1; sh < 16; sh <<= 1) {
            int o = __shfl_up(iv, sh);
            if (t >= sh) iv += o;
        }
        wexcl[t] = iv - w;
    }
    __syncthreads();
    int excl = wexcl[wid] + (v - s);              // global exclusive for thread
#pragma unroll
    for (int i = 0; i < 8; ++i) offs[t * 8 + i] = excl + loc[i];
    __syncthreads();
    for (int n = t; n < NTOK; n += 1024)
        sorted[offs[ids[n]] + pos[n]] = n;
}

// -------- Kernel F: EMA update via segment gather + renormalize + loss ---------
__global__ __launch_bounds__(256) void k_update(const float* __restrict__ zn,
                                                const float* __restrict__ emb,
                                                const float* __restrict__ cs,
                                                const int* __restrict__ bins,
                                                const int* __restrict__ offs,
                                                const int* __restrict__ sorted,
                                                const float* __restrict__ loss_part,
                                                float* __restrict__ out) {
    int idx = blockIdx.x * 256 + threadIdx.x;
    if (blockIdx.x == 0 && threadIdx.x < 64) {    // loss finalize (wave 0)
        float lp = loss_part[threadIdx.x];
#pragma unroll
        for (int sh = 32; sh > 0; sh >>= 1) lp += __shfl_down(lp, sh);
        if (threadIdx.x == 0) out[OUT_LOSS] = lp * (1.0f / 262144.0f);
    }
    int k = idx >> 5, c = idx & 31;
    int bi = bins[k];
    int off = offs[k];
    float t = 0.f;
    for (int i = 0; i < bi; ++i) {                // avg 1 iter
        int n = sorted[off + i];
        t += zn[(size_t)n * CDIM + c];            // coalesced 128B row
    }
    float bf = (float)bi;
    bool zero = (bi == 0);
    t /= (zero ? 1.0f : bf);
    float ss = t * t;
#pragma unroll
    for (int s = 1; s < 32; s <<= 1) ss += __shfl_xor(ss, s);
    float d = fmaxf(sqrtf(ss), 1e-12f);
    float ew = emb[idx];
    float en = zero ? ew : (t / d);
    float w = ew * DECAYF + (1.0f - DECAYF) * en;
    float ss2 = w * w;
#pragma unroll
    for (int s = 1; s < 32; s <<= 1) ss2 += __shfl_xor(ss2, s);
    float d2 = fmaxf(sqrtf(ss2), 1e-12f);
    out[OUT_EMB + idx] = w / d2;
    if (c == 0) out[OUT_CS + k] = cs[k] * DECAYF + (1.0f - DECAYF) * bf;
}

extern "C" void kernel_launch(void* const* d_in, const int* in_sizes, int n_in,
                              void* d_out, int out_size, void* d_ws, size_t ws_size,
                              hipStream_t stream) {
    const float* z   = (const float*)d_in[0];   // [32,32,16,16]
    const float* emb = (const float*)d_in[1];   // [8192,32]
    const float* cs  = (const float*)d_in[2];   // [8192]
    float* out = (float*)d_out;
    char* ws = (char*)d_ws;

    float* zn                  = (float*)(ws + WS_ZN);
    unsigned short* znbf       = (unsigned short*)(ws + WS_ZNBF);
    unsigned short* ebf        = (unsigned short*)(ws + WS_EBF);
    float* pmax                = (float*)(ws + WS_PMAX);
    unsigned long long* packed = (unsigned long long*)(ws + WS_PACK);
    int* bins                  = (int*)(ws + WS_BINS);
    float* loss_part           = (float*)(ws + WS_LOSSP);
    int* ids                   = (int*)(ws + WS_IDS);
    int* pos                   = (int*)(ws + WS_POS);
    int* offs                  = (int*)(ws + WS_OFFS);
    int* sorted                = (int*)(ws + WS_SORTED);

    hipMemsetAsync(ws + WS_PACK, 0, WS_ZERO_BYTES, stream);

    k_prep<<<dim3(160), 256, 0, stream>>>(z, emb, zn, znbf, ebf);
    k_max<<<dim3(NTOK / 256, NCHUNK), 256, 0, stream>>>(znbf, ebf, pmax);
    k_pick<<<dim3(NTOK / 256, NCHUNK), 256, 0, stream>>>(znbf, ebf, zn, emb, pmax, packed);
    k_postzq<<<dim3(1056), 256, 0, stream>>>(packed, zn, emb, bins, ids, pos, out, loss_part);
    k_scanplace<<<dim3(1), 1024, 0, stream>>>(bins, ids, pos, offs, sorted);
    k_update<<<dim3(1024), 256, 0, stream>>>(zn, emb, cs, bins, offs, sorted, loss_part, out);
}